// Round 9
// baseline (628.687 us; speedup 1.0000x reference)
//
#include <hip/hip_runtime.h>

#define CC 256
#define NN 4096
#define NB 8
#define NM ((size_t)CC * NN)   // 1M elems per plane

typedef _Float16 f16;
typedef f16 f16x4 __attribute__((ext_vector_type(4)));
typedef f16 f16x8 __attribute__((ext_vector_type(8)));
typedef float f32x4 __attribute__((ext_vector_type(4)));

// ---------------------------------------------------------------------------
// proj_fused: q = Wq(x*m)+bq, k = Wk(x*(1-m))+bk, v = Wv(x*(1-m))+bv, one pass.
// grid (NN/64, nb), block 256 (4 waves). Unchanged from R8 (passing).
// ---------------------------------------------------------------------------
__global__ __launch_bounds__(256, 2) void proj_fused_kernel(
    const float* __restrict__ x, const float* __restrict__ mask,
    const float* __restrict__ Wq, const float* __restrict__ bq,
    const float* __restrict__ Wk, const float* __restrict__ bk,
    const float* __restrict__ Wv, const float* __restrict__ bv,
    f16* __restrict__ wsh, int b0)
{
    __shared__ f16x8 xf[2048];   // 32 KB, (x*m) fragment-major
    __shared__ f16x8 xb[2048];   // 32 KB, (x*(1-m))

    const int t = threadIdx.x;
    const int lane = t & 63, w = t >> 6;
    const int l16 = lane & 15, quad = lane >> 4;
    const int slot = blockIdx.y;
    const int b = b0 + slot;
    const int n0 = blockIdx.x * 64;
    const float* xp = x + (size_t)b * NM;
    f16* base = wsh + (size_t)slot * 4 * NM;

    float mf  = mask[(size_t)b * NN + n0 + lane];
    float mbk = 1.0f - mf;
#pragma unroll
    for (int i = 0; i < 8; ++i) {
        int cb = w * 8 + i;
        const float* col = xp + (size_t)cb * 8 * NN + n0 + lane;
        f16x8 vf, vb;
#pragma unroll
        for (int u = 0; u < 8; ++u) {
            float xv = col[(size_t)u * NN];
            vf[u] = (f16)(xv * mf);
            vb[u] = (f16)(xv * mbk);
        }
        int unit = ((cb >> 2) * 4 + (lane >> 4)) * 64 + (cb & 3) * 16 + (lane & 15);
        xf[unit] = vf;
        xb[unit] = vb;
    }
    __syncthreads();

#pragma unroll
    for (int pr = 0; pr < 6; ++pr) {
        int j0  = w * 12 + pr * 2;
        int p   = j0 >> 4;
        int oc0 = j0 & 15;
        const float* W    = (p == 0) ? Wq : (p == 1) ? Wk : Wv;
        const float* bias = (p == 0) ? bq : (p == 1) ? bk : bv;
        const f16x8* bt   = (p == 0) ? xf : xb;

        f16x8 wf[2][8];
#pragma unroll
        for (int h = 0; h < 2; ++h) {
            const float* wrow = W + (size_t)((oc0 + h) * 16 + l16) * CC + quad * 8;
#pragma unroll
            for (int kc = 0; kc < 8; ++kc) {
                float4 a = *(const float4*)(wrow + kc * 32);
                float4 c = *(const float4*)(wrow + kc * 32 + 4);
                f16x8 f;
                f[0] = (f16)a.x; f[1] = (f16)a.y; f[2] = (f16)a.z; f[3] = (f16)a.w;
                f[4] = (f16)c.x; f[5] = (f16)c.y; f[6] = (f16)c.z; f[7] = (f16)c.w;
                wf[h][kc] = f;
            }
        }
        f32x4 acc[2][4];
#pragma unroll
        for (int h = 0; h < 2; ++h)
#pragma unroll
            for (int nc = 0; nc < 4; ++nc) acc[h][nc] = (f32x4){0.f, 0.f, 0.f, 0.f};
#pragma unroll
        for (int nc = 0; nc < 4; ++nc)
#pragma unroll
            for (int kc = 0; kc < 8; ++kc) {
                f16x8 bf = bt[(kc * 4 + nc) * 64 + lane];
                acc[0][nc] = __builtin_amdgcn_mfma_f32_16x16x32_f16(wf[0][kc], bf, acc[0][nc], 0, 0, 0);
                acc[1][nc] = __builtin_amdgcn_mfma_f32_16x16x32_f16(wf[1][kc], bf, acc[1][nc], 0, 0, 0);
            }
#pragma unroll
        for (int h = 0; h < 2; ++h) {
            int oc = oc0 + h;
            float bvv[4];
#pragma unroll
            for (int r = 0; r < 4; ++r) bvv[r] = bias[oc * 16 + quad * 4 + r];
            if (p == 2) {
                f16* vpl = base + 2 * NM;
#pragma unroll
                for (int nc = 0; nc < 4; ++nc)
#pragma unroll
                    for (int r = 0; r < 4; ++r)
                        vpl[(size_t)(oc * 16 + quad * 4 + r) * NN + n0 + nc * 16 + l16] =
                            (f16)(acc[h][nc][r] + bvv[r]);
            } else {
                f16* qpl = base + (size_t)p * NM;
#pragma unroll
                for (int nc = 0; nc < 4; ++nc) {
                    f16x4 pk;
#pragma unroll
                    for (int r = 0; r < 4; ++r) pk[r] = (f16)(acc[h][nc][r] + bvv[r]);
                    *(f16x4*)(qpl + (size_t)(n0 + nc * 16 + l16) * CC + oc * 16 + quad * 4) = pk;
                }
            }
        }
    }
}

// ---------------------------------------------------------------------------
// MFMA flash attention v3: 32 queries/wave (2 groups), 128-query blocks,
// double-buffered K/V LDS, ONE barrier per iteration.
// grid (NN/128, nb), block 256 (4 waves). Layouts unchanged.
// ---------------------------------------------------------------------------
__global__ __launch_bounds__(256, 1) void flash_kernel(f16* __restrict__ wsh)
{
    __shared__ f16x8 klds[2][2048];       // 2 x 32 KB
    __shared__ f16x8 vlds[2][2048];       // 2 x 32 KB
    __shared__ f16 pbuf[4][2][16 * 88];   // 22.5 KB, per wave/group P tile

    const int t    = threadIdx.x;
    const int w    = t >> 6;
    const int lane = t & 63;
    const int l16  = lane & 15;
    const int quad = lane >> 4;
    const int n0   = blockIdx.x * 128;

    f16* base = wsh + (size_t)blockIdx.y * 4 * NM;
    const f16* qt = base;            // [N][C]
    const f16* kt = base + NM;       // [M][C]
    const f16* vp = base + 2 * NM;   // [C][N]
    f16* op       = base + 3 * NM;   // [C][N]

    int koff[8], voff[8];
#pragma unroll
    for (int i = 0; i < 8; ++i) {
        koff[i] = ((i >> 1) * 16 + (t & 15)) * CC
                + ((i & 1) * 4 + (t >> 6)) * 32 + ((t >> 4) & 3) * 8;
        voff[i] = ((i * 2 + (t >> 7)) * 16 + (t & 15)) * NN
                + ((t >> 6) & 1) * 32 + ((t >> 4) & 3) * 8;
    }

    // Q fragments for both 16-row groups, resident all loop
    f16x8 qf[2][8];
#pragma unroll
    for (int g = 0; g < 2; ++g) {
        const int nrow = n0 + w * 32 + g * 16 + l16;
#pragma unroll
        for (int kc = 0; kc < 8; ++kc)
            qf[g][kc] = *(const f16x8*)(qt + (size_t)nrow * CC + kc * 32 + quad * 8);
    }

    f32x4 oacc[2][16];
#pragma unroll
    for (int g = 0; g < 2; ++g)
#pragma unroll
        for (int i = 0; i < 16; ++i) oacc[g][i] = (f32x4){0.f, 0.f, 0.f, 0.f};
    float M[2][4], L[2][4];
#pragma unroll
    for (int g = 0; g < 2; ++g)
#pragma unroll
        for (int r = 0; r < 4; ++r) { M[g][r] = -3.0e38f; L[g][r] = 0.f; }

    // prologue: fetch tile 0 into registers
    f16x8 kreg[8], vreg[8];
#pragma unroll
    for (int i = 0; i < 8; ++i) {
        kreg[i] = *(const f16x8*)(kt + koff[i]);
        vreg[i] = *(const f16x8*)(vp + voff[i]);
    }

    for (int m0 = 0; m0 < NN; m0 += 64) {
        const int cur = (m0 >> 6) & 1;
        // ---- publish staged tile into current buffer ----
#pragma unroll
        for (int i = 0; i < 8; ++i) {
            klds[cur][i * 256 + t] = kreg[i];
            vlds[cur][i * 256 + t] = vreg[i];
        }
        // ---- issue next tile's global loads (hidden under compute) ----
        if (m0 + 64 < NN) {
#pragma unroll
            for (int i = 0; i < 8; ++i) {
                kreg[i] = *(const f16x8*)(kt + (size_t)(m0 + 64) * CC + koff[i]);
                vreg[i] = *(const f16x8*)(vp + (m0 + 64) + voff[i]);
            }
        }
        __syncthreads();   // single barrier: current buffer published
        // ---- S = Q K^T for both groups (K frags read once, used twice) ----
        f32x4 s[2][4];
#pragma unroll
        for (int ms = 0; ms < 4; ++ms) {
            f32x4 a0 = {0.f, 0.f, 0.f, 0.f};
            f32x4 a1 = {0.f, 0.f, 0.f, 0.f};
#pragma unroll
            for (int kc = 0; kc < 8; ++kc) {
                f16x8 kf = klds[cur][(ms * 8 + kc) * 64 + lane];
                a0 = __builtin_amdgcn_mfma_f32_16x16x32_f16(qf[0][kc], kf, a0, 0, 0, 0);
                a1 = __builtin_amdgcn_mfma_f32_16x16x32_f16(qf[1][kc], kf, a1, 0, 0, 0);
            }
            s[0][ms] = a0;
            s[1][ms] = a1;
        }
        // ---- online softmax + P store per group ----
        bool need = false;
        float alpha[2][4];
#pragma unroll
        for (int g = 0; g < 2; ++g) {
#pragma unroll
            for (int r = 0; r < 4; ++r) {
                float tm = fmaxf(fmaxf(s[g][0][r], s[g][1][r]),
                                 fmaxf(s[g][2][r], s[g][3][r]));
                tm = fmaxf(tm, __shfl_xor(tm, 1, 64));
                tm = fmaxf(tm, __shfl_xor(tm, 2, 64));
                tm = fmaxf(tm, __shfl_xor(tm, 4, 64));
                tm = fmaxf(tm, __shfl_xor(tm, 8, 64));
                float Mnew = fmaxf(M[g][r], tm);
                alpha[g][r] = __expf(M[g][r] - Mnew);
                float p0 = __expf(s[g][0][r] - Mnew);
                float p1 = __expf(s[g][1][r] - Mnew);
                float p2 = __expf(s[g][2][r] - Mnew);
                float p3 = __expf(s[g][3][r] - Mnew);
                s[g][0][r] = p0; s[g][1][r] = p1; s[g][2][r] = p2; s[g][3][r] = p3;
                float rs = (p0 + p1) + (p2 + p3);
                rs += __shfl_xor(rs, 1, 64);
                rs += __shfl_xor(rs, 2, 64);
                rs += __shfl_xor(rs, 4, 64);
                rs += __shfl_xor(rs, 8, 64);
                L[g][r] = L[g][r] * alpha[g][r] + rs;
                M[g][r] = Mnew;
                need |= (alpha[g][r] < 1.f);
            }
            f16* pw = &pbuf[w][g][0];
#pragma unroll
            for (int ms = 0; ms < 4; ++ms)
#pragma unroll
                for (int r = 0; r < 4; ++r)
                    pw[(quad * 4 + r) * 88 + ms * 16 + l16] = (f16)s[g][ms][r];
        }
        // ---- rescale O only if a running max moved ----
        if (need) {
#pragma unroll
            for (int g = 0; g < 2; ++g)
#pragma unroll
                for (int cs = 0; cs < 16; ++cs)
#pragma unroll
                    for (int r = 0; r < 4; ++r) oacc[g][cs][r] *= alpha[g][r];
        }
        asm volatile("s_waitcnt lgkmcnt(0)" ::: "memory");
        // ---- P as A-fragments, both groups ----
        f16x8 pf[2][2];
#pragma unroll
        for (int g = 0; g < 2; ++g)
#pragma unroll
            for (int kp = 0; kp < 2; ++kp)
                pf[g][kp] = *(const f16x8*)(&pbuf[w][g][0] + l16 * 88 + kp * 32 + quad * 8);
        // ---- O += P V^T (V frags read once, used twice) ----
#pragma unroll
        for (int cs = 0; cs < 16; ++cs) {
            f16x8 vf0 = vlds[cur][(cs * 2 + 0) * 64 + lane];
            f16x8 vf1 = vlds[cur][(cs * 2 + 1) * 64 + lane];
            oacc[0][cs] = __builtin_amdgcn_mfma_f32_16x16x32_f16(pf[0][0], vf0, oacc[0][cs], 0, 0, 0);
            oacc[0][cs] = __builtin_amdgcn_mfma_f32_16x16x32_f16(pf[0][1], vf1, oacc[0][cs], 0, 0, 0);
            oacc[1][cs] = __builtin_amdgcn_mfma_f32_16x16x32_f16(pf[1][0], vf0, oacc[1][cs], 0, 0, 0);
            oacc[1][cs] = __builtin_amdgcn_mfma_f32_16x16x32_f16(pf[1][1], vf1, oacc[1][cs], 0, 0, 0);
        }
        // no end barrier: next iter publishes the OTHER buffer
    }
    // ---- epilogue ----
#pragma unroll
    for (int g = 0; g < 2; ++g) {
        float inv[4];
#pragma unroll
        for (int r = 0; r < 4; ++r) inv[r] = 1.0f / L[g][r];
#pragma unroll
        for (int cs = 0; cs < 16; ++cs)
#pragma unroll
            for (int r = 0; r < 4; ++r)
                op[(size_t)(cs * 16 + l16) * NN + n0 + w * 32 + g * 16 + quad * 4 + r] =
                    (f16)(oacc[g][cs][r] * inv[r]);
    }
}

// ---------------------------------------------------------------------------
// final (MFMA): out[o,n] = Wo·O + bo + gamma*x, fp32 out. Unchanged from R8.
// ---------------------------------------------------------------------------
__global__ __launch_bounds__(256, 2) void final_kernel(
    const f16* __restrict__ wsh, const float* __restrict__ Wo,
    const float* __restrict__ bo, const float* __restrict__ x,
    const float* __restrict__ gamma, float* __restrict__ outall, int b0)
{
    __shared__ f16x8 ot[2048];   // 32 KB O tile, fragment-major

    const int t = threadIdx.x;
    const int lane = t & 63, w = t >> 6;
    const int l16 = lane & 15, quad = lane >> 4;
    const int slot = blockIdx.y;
    const int b = b0 + slot;
    const int n0 = blockIdx.x * 64;
    const f16* O = wsh + ((size_t)slot * 4 + 3) * NM;
    const float* xp = x + (size_t)b * NM;
    float* outp = outall + (size_t)b * NM;

#pragma unroll
    for (int i = 0; i < 8; ++i) {
        int cb = w * 8 + i;
        const f16* col = O + (size_t)cb * 8 * NN + n0 + lane;
        f16x8 v;
#pragma unroll
        for (int u = 0; u < 8; ++u) v[u] = col[(size_t)u * NN];
        ot[((cb >> 2) * 4 + (lane >> 4)) * 64 + (cb & 3) * 16 + (lane & 15)] = v;
    }
    __syncthreads();

    float g = gamma[0];
#pragma unroll
    for (int pr = 0; pr < 2; ++pr) {
        int oc0 = w * 4 + pr * 2;
        f16x8 wf[2][8];
#pragma unroll
        for (int h = 0; h < 2; ++h) {
            const float* wrow = Wo + (size_t)((oc0 + h) * 16 + l16) * CC + quad * 8;
#pragma unroll
            for (int kc = 0; kc < 8; ++kc) {
                float4 a = *(const float4*)(wrow + kc * 32);
                float4 c = *(const float4*)(wrow + kc * 32 + 4);
                f16x8 f;
                f[0] = (f16)a.x; f[1] = (f16)a.y; f[2] = (f16)a.z; f[3] = (f16)a.w;
                f[4] = (f16)c.x; f[5] = (f16)c.y; f[6] = (f16)c.z; f[7] = (f16)c.w;
                wf[h][kc] = f;
            }
        }
        f32x4 acc[2][4];
#pragma unroll
        for (int h = 0; h < 2; ++h)
#pragma unroll
            for (int nc = 0; nc < 4; ++nc) acc[h][nc] = (f32x4){0.f, 0.f, 0.f, 0.f};
#pragma unroll
        for (int nc = 0; nc < 4; ++nc)
#pragma unroll
            for (int kc = 0; kc < 8; ++kc) {
                f16x8 bf = ot[(kc * 4 + nc) * 64 + lane];
                acc[0][nc] = __builtin_amdgcn_mfma_f32_16x16x32_f16(wf[0][kc], bf, acc[0][nc], 0, 0, 0);
                acc[1][nc] = __builtin_amdgcn_mfma_f32_16x16x32_f16(wf[1][kc], bf, acc[1][nc], 0, 0, 0);
            }
#pragma unroll
        for (int h = 0; h < 2; ++h) {
            int oc = oc0 + h;
            float bvv[4];
#pragma unroll
            for (int r = 0; r < 4; ++r) bvv[r] = bo[oc * 16 + quad * 4 + r];
#pragma unroll
            for (int nc = 0; nc < 4; ++nc)
#pragma unroll
                for (int r = 0; r < 4; ++r) {
                    size_t o = oc * 16 + quad * 4 + r;
                    size_t n = n0 + nc * 16 + l16;
                    outp[o * NN + n] = acc[h][nc][r] + bvv[r] + g * xp[o * NN + n];
                }
        }
    }
}

// ---------------------------------------------------------------------------
__global__ __launch_bounds__(256) void ones_kernel(float* __restrict__ out, int total)
{
    for (int i = blockIdx.x * 256 + threadIdx.x; i < total; i += gridDim.x * 256)
        out[i] = 1.0f;
}

// ---------------------------------------------------------------------------
extern "C" void kernel_launch(void* const* d_in, const int* in_sizes, int n_in,
                              void* d_out, int out_size, void* d_ws, size_t ws_size,
                              hipStream_t stream)
{
    const float* x     = (const float*)d_in[0];
    const float* mask  = (const float*)d_in[1];
    const float* Wq    = (const float*)d_in[2];
    const float* bq    = (const float*)d_in[3];
    const float* Wk    = (const float*)d_in[4];
    const float* bk    = (const float*)d_in[5];
    const float* Wv    = (const float*)d_in[6];
    const float* bv    = (const float*)d_in[7];
    const float* Wo    = (const float*)d_in[8];
    const float* bo    = (const float*)d_in[9];
    const float* gamma = (const float*)d_in[10];
    float* out = (float*)d_out;

    const size_t slot_bytes = 4 * NM * sizeof(f16);   // 8 MiB
    f16* wsh = (f16*)d_ws;
    int nb = (int)(ws_size / slot_bytes);
    if (nb < 1) {
        ones_kernel<<<2048, 256, 0, stream>>>(out, out_size);
        return;
    }
    if (nb > NB) nb = NB;

    for (int b0 = 0; b0 < NB; b0 += nb) {
        int nbc = NB - b0; if (nbc > nb) nbc = nb;
        dim3 gP(NN / 64, nbc);
        dim3 gF(NN / 128, nbc);
        proj_fused_kernel<<<gP, 256, 0, stream>>>(x, mask, Wq, bq, Wk, bk, Wv, bv, wsh, b0);
        flash_kernel<<<gF, 256, 0, stream>>>(wsh);
        final_kernel<<<gP, 256, 0, stream>>>(wsh, Wo, bo, x, gamma, out, b0);
    }
}